// Round 10
// baseline (81.136 us; speedup 1.0000x reference)
//
#include <hip/hip_runtime.h>

// DensityLoss: B=8, N=4096, radius=0.1, NSAMPLE=9, TOPK=5, H=0.12, EPS=1e-12
// Output: scalar mean over [B,N,TOPK-1] of (RADIUS - sqrt(ds)*exp(-ds/H^2))
//
// R10 = R8 (best known: brute-force in-order scan, 4 queries/wave, packed
// v2f math, transposed-SoA LDS, absmax 0.0) + two scan-loop changes:
//  1. software pipelining: group g+1's three float4 LDS reads issue before
//     group g's compute -> ds_read latency overlapped instead of exposed
//     once per 256 candidates.
//  2. any-hit fast path: per query per group, min of the 4 packed ds values
//     vs r^2 (3 v_min + 1 ballot). Zero qualifiers among the 256 candidates
//     -> skip the 4 ballot/step sequences entirely. Exact: count and slot
//     writes are unchanged when no lane qualifies. E[hits/group] ~= 1.06;
//     for late-surviving (boundary, low-density) queries P(no-hit) ~= 75%.

#define NB 8
#define NPTS 4096
#define NS 9
#define RAD2 0.01f
#define H2 0.0144f
#define EPSV 1e-12f
#define SCALE (1.0f / 131072.0f)   // 1/(B*N*(TOPK-1)) = 1/(8*4096*4)

typedef float v2f __attribute__((ext_vector_type(2)));

__device__ __forceinline__ void step(float val, int& cnt, float* row) {
    bool q = (val <= RAD2);
    unsigned long long m = __ballot(q);
    if (m) {                       // wave-uniform -> s_cbranch
        if (q) {                   // exec-masked
            unsigned r = __builtin_amdgcn_mbcnt_lo((unsigned)m, 0u);
            r = __builtin_amdgcn_mbcnt_hi((unsigned)(m >> 32), r);
            int slot = cnt + (int)r;
            if (slot < NS) row[slot] = val;
        }
        cnt += (int)__popcll(m);   // scalar (s_bcnt1)
    }
}

__global__ __launch_bounds__(1024) void density_loss_kernel(
    const float* __restrict__ pred, float* __restrict__ part) {
    __shared__ __align__(16) float sh[3 * NPTS];   // 48 KB transposed SoA
    __shared__ __align__(16) float buf[64][NS];    // per-point neighbor slots
    __shared__ __align__(16) int cnts[64];

    const int tid   = threadIdx.x;
    const int lane  = tid & 63;
    const int wid   = tid >> 6;
    const int b     = blockIdx.x >> 6;                       // 64 blocks/batch
    const int nbase = ((blockIdx.x & 63) << 6) + (wid << 2); // 4 queries/wave

    // ---- Stage: strided global float3 reads -> contiguous b128 LDS writes.
    // Block-transposed SoA: candidate c at (c & ~255) + ((c&63)<<2) + ((c>>6)&3)
    // per plane; lane L's float4 in group g = candidates {g*256+L,+64,+128,+192}.
    {
        const float* src = pred + (size_t)b * (NPTS * 3);
        const int cbase = (wid << 8) + lane;
        float xs[4], ys[4], zs[4];
        #pragma unroll
        for (int k = 0; k < 4; ++k) {
            const float* p = src + 3 * (cbase + (k << 6));
            xs[k] = p[0]; ys[k] = p[1]; zs[k] = p[2];
        }
        *(float4*)(sh + (tid << 2))            = (float4){xs[0], xs[1], xs[2], xs[3]};
        *(float4*)(sh + NPTS + (tid << 2))     = (float4){ys[0], ys[1], ys[2], ys[3]};
        *(float4*)(sh + 2 * NPTS + (tid << 2)) = (float4){zs[0], zs[1], zs[2], zs[3]};
    }
    __syncthreads();

    // Query coords (wave-uniform -> scalarizable)
    float qx[4], qy[4], qz[4];
    #pragma unroll
    for (int q = 0; q < 4; ++q) {
        int n = nbase + q;
        int p = (n & ~255) | ((n & 63) << 2) | ((n >> 6) & 3);
        qx[q] = sh[p]; qy[q] = sh[NPTS + p]; qz[q] = sh[2 * NPTS + p];
    }

    // ---- Scan: 256 candidates/group via 3x ds_read_b128, shared across the
    // wave's 4 query points; pipelined (next group's reads in flight during
    // current group's compute). Sub-chunks k=0..3 in index order.
    int c0 = 0, c1 = 0, c2 = 0, c3 = 0;
    const float* pl = sh + (lane << 2);
    float4 xa = *(const float4*)pl;
    float4 ya = *(const float4*)(pl + NPTS);
    float4 za = *(const float4*)(pl + 2 * NPTS);
    for (int g = 0; g < NPTS / 256; ++g) {
        float4 xn, yn, zn;
        if (g + 1 < NPTS / 256) {          // prefetch next group
            const float* pn = pl + 256;
            xn = *(const float4*)pn;
            yn = *(const float4*)(pn + NPTS);
            zn = *(const float4*)(pn + 2 * NPTS);
        }
        v2f xl = {xa.x, xa.y}, xh = {xa.z, xa.w};
        v2f yl = {ya.x, ya.y}, yh = {ya.z, ya.w};
        v2f zl = {za.x, za.y}, zh = {za.z, za.w};
        #pragma unroll
        for (int q = 0; q < 4; ++q) {
            int& cq = (q == 0) ? c0 : (q == 1) ? c1 : (q == 2) ? c2 : c3;
            if (cq >= NS) continue;          // wave-uniform skip (point done)
            v2f px = {qx[q], qx[q]}, py = {qy[q], qy[q]}, pz = {qz[q], qz[q]};
            v2f dxl = xl - px, dyl = yl - py, dzl = zl - pz;
            v2f dxh = xh - px, dyh = yh - py, dzh = zh - pz;
            v2f dl = dxl * dxl + dyl * dyl + dzl * dzl;
            v2f dh = dxh * dxh + dyh * dyh + dzh * dzh;
            // Any-hit fast path: no lane has a qualifier among these 256
            // candidates for query q -> skip the 4 step()s (exact: no count
            // or slot changes are possible).
            float mn = fminf(fminf(dl.x, dl.y), fminf(dh.x, dh.y));
            if (__ballot(mn <= RAD2) == 0ull) continue;
            float* row = buf[(wid << 2) + q];
            step(dl.x, cq, row);
            step(dl.y, cq, row);
            step(dh.x, cq, row);
            step(dh.y, cq, row);
        }
        if (c0 >= NS && c1 >= NS && c2 >= NS && c3 >= NS) break;
        xa = xn; ya = yn; za = zn;
        pl += 256;
    }
    if (lane == 0)
        *(int4*)(cnts + (wid << 2)) = (int4){c0, c1, c2, c3};
    __syncthreads();

    // ---- Epilogue: lane i of wave 0 handles block point i.
    if (tid < 64) {
        int cnt = cnts[tid]; if (cnt > NS) cnt = NS;   // cnt >= 1 (self)
        float s[NS];
        float first = buf[tid][0];
        #pragma unroll
        for (int j = 0; j < NS; ++j) {
            float v = buf[tid][j];
            s[j] = (j < cnt) ? v : first;
        }
        // Partial selection sort: smallest 5 ascending into s[0..4]
        #pragma unroll
        for (int i = 0; i < 5; ++i) {
            #pragma unroll
            for (int j = i + 1; j < NS; ++j) {
                float lo = fminf(s[i], s[j]);
                float hi = fmaxf(s[i], s[j]);
                s[i] = lo; s[j] = hi;
            }
        }
        float acc = 0.0f;
        #pragma unroll
        for (int i = 1; i < 5; ++i) {
            float c = (s[i] < EPSV) ? EPSV : s[i];
            acc += 0.1f - sqrtf(c) * expf(-c / H2);
        }
        #pragma unroll
        for (int off = 32; off >= 1; off >>= 1)
            acc += __shfl_down(acc, off, 64);
        if (tid == 0) part[blockIdx.x] = acc;   // plain store, no atomic
    }
}

__global__ __launch_bounds__(512) void reduce_kernel(
    const float* __restrict__ part, float* __restrict__ out) {
    __shared__ float w[8];
    const int tid = threadIdx.x;
    float s = part[tid];               // 512 partials, 512 threads
    #pragma unroll
    for (int o = 32; o >= 1; o >>= 1)
        s += __shfl_down(s, o, 64);
    if ((tid & 63) == 0) w[tid >> 6] = s;
    __syncthreads();
    if (tid == 0) {
        float t = 0.0f;
        #pragma unroll
        for (int i = 0; i < 8; ++i) t += w[i];
        out[0] = t * SCALE;
    }
}

extern "C" void kernel_launch(void* const* d_in, const int* in_sizes, int n_in,
                              void* d_out, int out_size, void* d_ws, size_t ws_size,
                              hipStream_t stream) {
    const float* pred = (const float*)d_in[0];
    float* out = (float*)d_out;
    float* part = (float*)d_ws;        // 512 floats of the workspace
    density_loss_kernel<<<dim3(NB * 64), dim3(1024), 0, stream>>>(pred, part);
    reduce_kernel<<<dim3(1), dim3(512), 0, stream>>>(part, out);
}